// Round 7
// baseline (549.077 us; speedup 1.0000x reference)
//
#include <hip/hip_runtime.h>

#define BB   64
#define S    2048
#define HH   128
#define KCH  682
#define EPS  1e-5f

// ================= MFMA path =================
#define TT2   48          // output t per block (16 chunks)
#define NTB2  43          // ceil(2046/48)
#define NROWS 66          // h rows: t in [t0-3, t0+63)

typedef __attribute__((ext_vector_type(8))) short bf16x8;
typedef __attribute__((ext_vector_type(4))) short bf16x4v;
typedef __attribute__((ext_vector_type(4))) float f32x4;

__device__ __forceinline__ unsigned short bf16hi(float v) {
    return (unsigned short)(__float_as_uint(v) >> 16);
}
__device__ __forceinline__ float bf16f(unsigned short h) {
    return __uint_as_float(((unsigned)h) << 16);
}

// Pack W fragments in exact MFMA A-operand order (row=lane&15, k=(lane>>4)*8+j).
// Layout: frag_idx = ((mat*12+kb)*8+mc)*2+pl ; 512 ushort per frag (64 lanes x 8).
__global__ void pack_w_frags(const float* __restrict__ w1, const float* __restrict__ w2,
                             const float* __restrict__ pw, unsigned short* __restrict__ wpk) {
    int u = blockIdx.x * 256 + threadIdx.x;     // 18432 units
    if (u >= 18432) return;
    int lane = u & 63, mc = (u >> 6) & 7, kb = (u >> 9) % 12, mat = u / 6144;
    const float* src = (mat == 0) ? w1 : (mat == 1) ? w2 : pw;
    int c = mc * 16 + (lane & 15);
    int kbase = kb * 32 + ((lane >> 4) << 3);
    bf16x8 hv, lv;
    #pragma unroll
    for (int j = 0; j < 8; ++j) {
        int k = kbase + j, tap = k >> 7, ci = k & 127;   // K = tap*128 + ci
        float v = src[c * 384 + ci * 3 + tap];
        unsigned short h = bf16hi(v);
        float r = v - bf16f(h);
        hv[j] = (short)h;
        lv[j] = (short)bf16hi(r);
    }
    int fb = ((mat * 12 + kb) * 8 + mc) * 2;
    *(bf16x8*)(wpk + (size_t)(fb + 0) * 512 + lane * 8) = hv;
    *(bf16x8*)(wpk + (size_t)(fb + 1) * 512 + lane * 8) = lv;
}

__device__ __forceinline__ int read_seqlen(const int* seq, int b) {
    bool is64 = true;
    for (int i = 1; i < 64; i += 2) { if (seq[i] != 0) { is64 = false; break; } }
    return is64 ? seq[2 * b] : seq[b];
}

// swizzled byte address into a [NROWS][128] ushort plane: row rr, 16B-chunk index
__device__ __forceinline__ int haddr(int rr, int chunk) {
    return (rr << 8) | ((chunk ^ (rr & 15)) << 4);
}

// 4 c-tiles x up-to-2 n-tiles per wave. B rows = rbase + tap + (lane&15) + nt*16.
// B hi/lo pair amortized over 12 MFMAs (4 c-tiles) -> half the LDS reads of r6.
__device__ __forceinline__ void conv_k22(
        f32x4 (&acc)[4][2], const unsigned short* __restrict__ wpk, int mat,
        const unsigned short* __restrict__ hHi, const unsigned short* __restrict__ hLo,
        int cg, int nt_base, int nt_lim, int rbase, int lane) {
    #pragma unroll
    for (int i = 0; i < 4; ++i)
        #pragma unroll
        for (int j = 0; j < 2; ++j) acc[i][j] = (f32x4){0.f, 0.f, 0.f, 0.f};

    const bf16x8* wp = (const bf16x8*)wpk;
    for (int kb = 0; kb < 12; ++kb) {
        const int fb = ((mat * 12 + kb) * 8 + cg * 4) * 2;   // this wave's 4 c-tiles
        bf16x8 ah[4], al[4];
        #pragma unroll
        for (int i = 0; i < 4; ++i) {
            ah[i] = wp[(size_t)(fb + 2 * i) * 64 + lane];
            al[i] = wp[(size_t)(fb + 2 * i + 1) * 64 + lane];
        }
        const int tap = kb >> 2;
        const int chunk = (kb & 3) * 4 + (lane >> 4);
        const int rr0 = rbase + tap + (lane & 15);
        __builtin_amdgcn_s_setprio(1);
        #pragma unroll
        for (int j = 0; j < 2; ++j) {
            const int nt = nt_base + j;
            if (nt < nt_lim) {
                const int ad = haddr(rr0 + nt * 16, chunk);
                bf16x8 bh = *(const bf16x8*)((const char*)hHi + ad);
                bf16x8 bl = *(const bf16x8*)((const char*)hLo + ad);
                #pragma unroll
                for (int i = 0; i < 4; ++i) {
                    acc[i][j] = __builtin_amdgcn_mfma_f32_16x16x32_bf16(ah[i], bh, acc[i][j], 0, 0, 0);
                    acc[i][j] = __builtin_amdgcn_mfma_f32_16x16x32_bf16(al[i], bh, acc[i][j], 0, 0, 0);
                    acc[i][j] = __builtin_amdgcn_mfma_f32_16x16x32_bf16(ah[i], bl, acc[i][j], 0, 0, 0);
                }
            }
        }
        __builtin_amdgcn_s_setprio(0);
    }
}

// BN+relu epilogue for the 4c x 2n wave tiling
template<int ROW_OFF, int T_OFF>
__device__ __forceinline__ void epi22(
        f32x4 (&acc)[4][2], const float* __restrict__ bias,
        const float* __restrict__ bng, const float* __restrict__ bnb,
        const float* __restrict__ bnm, const float* __restrict__ bnv, int layer,
        unsigned short* __restrict__ hHi, unsigned short* __restrict__ hLo,
        int cg, int nt_base, int nt_lim, int lane, int t0) {
    #pragma unroll
    for (int i = 0; i < 4; ++i) {
        const int c0 = cg * 64 + i * 16 + (lane >> 4) * 4;
        const float4 bv = *(const float4*)&bias[c0];
        const float4 g  = *(const float4*)&bng[layer * 128 + c0];
        const float4 be = *(const float4*)&bnb[layer * 128 + c0];
        const float4 mn = *(const float4*)&bnm[layer * 128 + c0];
        const float4 vr = *(const float4*)&bnv[layer * 128 + c0];
        const float av[4] = { g.x * rsqrtf(vr.x + EPS), g.y * rsqrtf(vr.y + EPS),
                              g.z * rsqrtf(vr.z + EPS), g.w * rsqrtf(vr.w + EPS) };
        const float dv[4] = { be.x - mn.x * av[0], be.y - mn.y * av[1],
                              be.z - mn.z * av[2], be.w - mn.w * av[3] };
        const float bb[4] = { bv.x, bv.y, bv.z, bv.w };
        const int byte = c0 * 2, chunk = byte >> 4, off = byte & 15;
        #pragma unroll
        for (int j = 0; j < 2; ++j) {
            const int nt = nt_base + j;
            if (nt < nt_lim) {
                const int tt = nt * 16 + (lane & 15);
                const int t = t0 + T_OFF + tt;
                const int rr = tt + ROW_OFF;
                const bool ok = (t >= 0) && (t < S);
                bf16x4v h4, l4;
                #pragma unroll
                for (int r = 0; r < 4; ++r) {
                    float v = 0.f;
                    if (ok) v = fmaf(fmaxf(acc[i][j][r] + bb[r], 0.f), av[r], dv[r]);
                    unsigned short h = bf16hi(v);
                    float res = v - bf16f(h);
                    h4[r] = (short)h;
                    l4[r] = (short)bf16hi(res);
                }
                const int ad = haddr(rr, chunk) | off;
                *(bf16x4v*)((char*)hHi + ad) = h4;
                *(bf16x4v*)((char*)hLo + ad) = l4;
            }
        }
    }
}

__global__ __launch_bounds__(256, 4)
void fused_mfma(const float* __restrict__ x, const int* __restrict__ seq,
                const float* __restrict__ w0, const float* __restrict__ b0,
                const float* __restrict__ b1, const float* __restrict__ b2,
                const float* __restrict__ bng, const float* __restrict__ bnb,
                const float* __restrict__ bnm, const float* __restrict__ bnv,
                const float* __restrict__ pb, const float* __restrict__ fcw,
                const float* __restrict__ fcb, const unsigned short* __restrict__ wpk,
                float* __restrict__ out) {
    __shared__ __align__(16) unsigned short hHi[NROWS * 128];   // 16896 B
    __shared__ __align__(16) unsigned short hLo[NROWS * 128];   // 16896 B
    __shared__ __align__(16) float xs[72];
    __shared__ float p0[6 * 128];
    __shared__ float zred[2][16];
    __shared__ int nch_s;

    const int tid = threadIdx.x;
    const int lane = tid & 63, wv = tid >> 6;
    const int cg = wv & 1, ng = wv >> 1;      // 2 c-groups x 2 n-groups
    const int b  = blockIdx.x / NTB2;
    const int jt = blockIdx.x - b * NTB2;
    const int t0 = jt * TT2;

    // ---- stage x (t0-4 .. t0+63) + conv0/bn0 per-channel constants ----
    if (tid < 68) {
        const int t = t0 - 4 + tid;
        xs[tid] = (t >= 0 && t < S) ? x[b * S + t] : 0.f;
    }
    if (tid < 128) {
        const int c = tid;
        p0[c]         = w0[c * 3 + 0];
        p0[128 + c]   = w0[c * 3 + 1];
        p0[2*128 + c] = w0[c * 3 + 2];
        p0[3*128 + c] = b0[c];
        const float a0 = bng[c] * rsqrtf(bnv[c] + EPS);
        p0[4*128 + c] = a0;
        p0[5*128 + c] = bnb[c] - bnm[c] * a0;
    }
    if (tid == 0) nch_s = read_seqlen(seq, b) / 3;
    __syncthreads();

    // ---- conv0 + bn0 -> h1 rows rr=0..65 (t = t0-3+rr), bf16 hi/lo ----
    for (int it = 0; it < 5; ++it) {
        const int u = tid + it * 256;              // 1056 units = 66 rows x 16 octets
        if (u < NROWS * 16) {
            const int rr = u >> 4, oct = u & 15, ci0 = oct * 8;
            const int t = t0 - 3 + rr;
            const bool ok = (t >= 0) && (t < S);
            const float xm = xs[rr], xc = xs[rr + 1], xp = xs[rr + 2];
            bf16x8 hv, lv;
            #pragma unroll
            for (int q = 0; q < 8; ++q) {
                const int c = ci0 + q;
                float v = 0.f;
                if (ok) {
                    float sa = fmaf(xp, p0[2*128 + c],
                               fmaf(xc, p0[128 + c],
                               fmaf(xm, p0[c], p0[3*128 + c])));
                    v = fmaf(fmaxf(sa, 0.f), p0[4*128 + c], p0[5*128 + c]);
                }
                unsigned short h = bf16hi(v);
                float res = v - bf16f(h);
                hv[q] = (short)h;
                lv[q] = (short)bf16hi(res);
            }
            const int ad = haddr(rr, oct);
            *(bf16x8*)((char*)hHi + ad) = hv;
            *(bf16x8*)((char*)hLo + ad) = lv;
        }
    }
    __syncthreads();

    f32x4 acc[4][2];

    // ---- conv1: 4 nt; ng owns {2ng, 2ng+1}. B rows 0..65 -> out rows tt+1 (1..64) ----
    conv_k22(acc, wpk, 0, hHi, hLo, cg, ng * 2, 4, 0, lane);
    __syncthreads();                            // all h1 reads done
    epi22<1, -2>(acc, b1, bng, bnb, bnm, bnv, 1, hHi, hLo, cg, ng * 2, 4, lane, t0);
    __syncthreads();

    // ---- conv2: 3 nt; ng0 owns {0,1}, ng1 owns {2}. B rows 2..51 -> out rows tt+3 (3..50) ----
    conv_k22(acc, wpk, 1, hHi, hLo, cg, ng * 2, 3, 2, lane);
    __syncthreads();                            // all h2 reads done
    epi22<3, 0>(acc, b2, bng, bnb, bnm, bnv, 2, hHi, hLo, cg, ng * 2, 3, lane, t0);
    __syncthreads();

    // ---- pre einsum: ng0 waves only (full 12 kb so relu sees complete z); cg splits o ----
    if (ng == 0) {
        f32x4 pacc[4];
        #pragma unroll
        for (int i = 0; i < 4; ++i) pacc[i] = (f32x4){0.f, 0.f, 0.f, 0.f};
        const bf16x8* wp = (const bf16x8*)wpk;
        const int klocal = lane & 15;
        for (int kb = 0; kb < 12; ++kb) {
            const int fb = ((2 * 12 + kb) * 8 + cg * 4) * 2;
            bf16x8 ah[4], al[4];
            #pragma unroll
            for (int i = 0; i < 4; ++i) {
                ah[i] = wp[(size_t)(fb + 2 * i) * 64 + lane];
                al[i] = wp[(size_t)(fb + 2 * i + 1) * 64 + lane];
            }
            const int tap = kb >> 2;
            const int chunk = (kb & 3) * 4 + (lane >> 4);
            const int rr = 3 + 3 * klocal + tap;          // h3 row for t = t0+3k+tap
            const int ad = haddr(rr, chunk);
            bf16x8 bh = *(const bf16x8*)((const char*)hHi + ad);
            bf16x8 bl = *(const bf16x8*)((const char*)hLo + ad);
            __builtin_amdgcn_s_setprio(1);
            #pragma unroll
            for (int i = 0; i < 4; ++i) {
                pacc[i] = __builtin_amdgcn_mfma_f32_16x16x32_bf16(ah[i], bh, pacc[i], 0, 0, 0);
                pacc[i] = __builtin_amdgcn_mfma_f32_16x16x32_bf16(al[i], bh, pacc[i], 0, 0, 0);
                pacc[i] = __builtin_amdgcn_mfma_f32_16x16x32_bf16(ah[i], bl, pacc[i], 0, 0, 0);
            }
            __builtin_amdgcn_s_setprio(0);
        }

        // relu(z+pb)*fcw over this wave's 64 o-channels, full z (all 12 kb) per lane
        float s0 = 0.f;
        #pragma unroll
        for (int i = 0; i < 4; ++i) {
            const int o0 = cg * 64 + i * 16 + (lane >> 4) * 4;
            const float4 pbv = *(const float4*)&pb[o0];
            const float4 fwv = *(const float4*)&fcw[o0];
            const float pbb[4] = { pbv.x, pbv.y, pbv.z, pbv.w };
            const float fww[4] = { fwv.x, fwv.y, fwv.z, fwv.w };
            #pragma unroll
            for (int r = 0; r < 4; ++r)
                s0 += fmaxf(pacc[i][r] + pbb[r], 0.f) * fww[r];
        }
        s0 += __shfl_xor(s0, 16);
        s0 += __shfl_xor(s0, 32);                  // sum over o within wave's 64 channels
        if (lane < 16) zred[cg][lane] = s0;        // k = lane
    }
    __syncthreads();
    if (tid < 16) {
        const float zz = zred[0][tid] + zred[1][tid];
        const int kG = jt * 16 + tid;
        if (kG < KCH)
            out[b * KCH + kG] = (kG < nch_s) ? (zz + fcb[0]) : 0.f;
    }
}

// ================= fp32 fallback (round-3 verified) =================
#define TT   78
#define NTB  27
#define STRIDE 84

__device__ __forceinline__ void stage_w_fb(float* __restrict__ wtS,
                                           const float* __restrict__ wraw, int cc, int tid) {
    for (int i = tid; i < 6144; i += 256)
        wtS[i] = wraw[(i & 127) * 384 + cc * 3 + (i >> 7)];
}

__device__ __forceinline__ void conv_gemm_fb(float (&acc)[10][4],
                                             const float* __restrict__ wraw,
                                             const float* __restrict__ hAp,
                                             float* __restrict__ wtS,
                                             int tid, int c0, int tbase) {
    #pragma unroll
    for (int i = 0; i < 10; ++i)
        #pragma unroll
        for (int q = 0; q < 4; ++q) acc[i][q] = 0.f;
    for (int cc = 0; cc < HH; cc += 16) {
        __syncthreads();
        stage_w_fb(wtS, wraw, cc, tid);
        __syncthreads();
        for (int ci = 0; ci < 16; ++ci) {
            float hr[12];
            #pragma unroll
            for (int j = 0; j < 12; ++j) hr[j] = hAp[(cc + ci) * STRIDE + tbase + j];
            #pragma unroll
            for (int tap = 0; tap < 3; ++tap) {
                const float4 w = *(const float4*)&wtS[((ci * 3 + tap) << 7) + c0];
                #pragma unroll
                for (int i = 0; i < 10; ++i) {
                    const float h = hr[i + tap];
                    acc[i][0] = fmaf(h, w.x, acc[i][0]);
                    acc[i][1] = fmaf(h, w.y, acc[i][1]);
                    acc[i][2] = fmaf(h, w.z, acc[i][2]);
                    acc[i][3] = fmaf(h, w.w, acc[i][3]);
                }
            }
        }
    }
}

__global__ __launch_bounds__(256, 2)
void fused_pd(const float* __restrict__ x, const int* __restrict__ seq,
              const float* __restrict__ w0, const float* __restrict__ b0,
              const float* __restrict__ w1raw, const float* __restrict__ b1,
              const float* __restrict__ w2raw, const float* __restrict__ b2,
              const float* __restrict__ bng, const float* __restrict__ bnb,
              const float* __restrict__ bnm, const float* __restrict__ bnv,
              const float* __restrict__ pwraw, const float* __restrict__ pb,
              const float* __restrict__ fcw, const float* __restrict__ fcb,
              float* __restrict__ out) {
    __shared__ __align__(16) float hA[HH * STRIDE];
    __shared__ __align__(16) float wtS[6144];
    __shared__ __align__(16) float xsf[TT + 8];
    __shared__ int nch_s;

    const int tid = threadIdx.x;
    const int b  = blockIdx.x / NTB;
    const int jt = blockIdx.x - b * NTB;
    const int t0 = jt * TT;

    for (int j = tid; j < TT + 6; j += 256) {
        const int t = t0 - 3 + j;
        xsf[j] = (t >= 0 && t < S) ? x[b * S + t] : 0.f;
    }
    if (tid == 0) nch_s = read_seqlen(seq, b) / 3;

    const int cch = tid & 127;
    const float w0a = w0[cch * 3 + 0], w0b = w0[cch * 3 + 1], w0c = w0[cch * 3 + 2];
    const float bb0 = b0[cch];
    const float a0 = bng[cch] * rsqrtf(bnv[cch] + EPS);
    const float d0 = bnb[cch] - bnm[cch] * a0;
    __syncthreads();

    for (int i = tid; i < (TT + 4) * HH; i += 256) {
        const int ttl = i >> 7;
        const int t = t0 - 2 + ttl;
        float v = 0.f;
        if (t >= 0 && t < S) {
            float sa = fmaf(xsf[ttl + 2], w0c, fmaf(xsf[ttl + 1], w0b, fmaf(xsf[ttl], w0a, bb0)));
            v = fmaf(fmaxf(sa, 0.f), a0, d0);
        }
        hA[cch * STRIDE + ttl] = v;
    }

    const int cg = tid & 31, tg = tid >> 5;
    const int c0 = cg * 4;
    const int tbase = tg * 10;
    float acc[10][4];

    conv_gemm_fb(acc, w1raw, hA, wtS, tid, c0, tbase);
    {
        const float4 bv = *(const float4*)&b1[c0];
        const float4 g  = *(const float4*)&bng[HH + c0];
        const float4 be = *(const float4*)&bnb[HH + c0];
        const float4 mn = *(const float4*)&bnm[HH + c0];
        const float4 vr = *(const float4*)&bnv[HH + c0];
        float av[4] = { g.x * rsqrtf(vr.x + EPS), g.y * rsqrtf(vr.y + EPS),
                        g.z * rsqrtf(vr.z + EPS), g.w * rsqrtf(vr.w + EPS) };
        float dv[4] = { be.x - mn.x * av[0], be.y - mn.y * av[1],
                        be.z - mn.z * av[2], be.w - mn.w * av[3] };
        float bb[4] = { bv.x, bv.y, bv.z, bv.w };
        __syncthreads();
        #pragma unroll
        for (int i = 0; i < 10; ++i) {
            const int tt2 = tbase + i;
            const int t = t0 - 1 + tt2;
            const bool ok = (t >= 0) && (t < S);
            #pragma unroll
            for (int q = 0; q < 4; ++q) {
                float v = 0.f;
                if (ok) v = fmaf(fmaxf(acc[i][q] + bb[q], 0.f), av[q], dv[q]);
                hA[(c0 + q) * STRIDE + tt2] = v;
            }
        }
        __syncthreads();
    }

    conv_gemm_fb(acc, w2raw, hA, wtS, tid, c0, tbase);
    {
        const float4 bv = *(const float4*)&b2[c0];
        const float4 g  = *(const float4*)&bng[2 * HH + c0];
        const float4 be = *(const float4*)&bnb[2 * HH + c0];
        const float4 mn = *(const float4*)&bnm[2 * HH + c0];
        const float4 vr = *(const float4*)&bnv[2 * HH + c0];
        float av[4] = { g.x * rsqrtf(vr.x + EPS), g.y * rsqrtf(vr.y + EPS),
                        g.z * rsqrtf(vr.z + EPS), g.w * rsqrtf(vr.w + EPS) };
        float dv[4] = { be.x - mn.x * av[0], be.y - mn.y * av[1],
                        be.z - mn.z * av[2], be.w - mn.w * av[3] };
        float bb[4] = { bv.x, bv.y, bv.z, bv.w };
        __syncthreads();
        #pragma unroll
        for (int i = 0; i < 10; ++i) {
            const int tt3 = tbase + i;
            if (tt3 < TT) {
                const int t = t0 + tt3;
                #pragma unroll
                for (int q = 0; q < 4; ++q) {
                    float vv = 0.f;
                    if (t < S) vv = fmaf(fmaxf(acc[i][q] + bb[q], 0.f), av[q], dv[q]);
                    hA[(c0 + q) * STRIDE + tt3] = vv;
                }
            }
        }
        __syncthreads();
    }

    const int og = tid & 31, kg = tid >> 5;
    const int oo = og * 4;
    float pacc[4][4];
    #pragma unroll
    for (int j = 0; j < 4; ++j)
        #pragma unroll
        for (int q = 0; q < 4; ++q) pacc[j][q] = 0.f;

    for (int hc = 0; hc < HH; hc += 16) {
        __syncthreads();
        stage_w_fb(wtS, pwraw, hc, tid);
        __syncthreads();
        for (int h = 0; h < 16; ++h) {
            #pragma unroll
            for (int tap = 0; tap < 3; ++tap) {
                const float4 w = *(const float4*)&wtS[((h * 3 + tap) << 7) + oo];
                #pragma unroll
                for (int j = 0; j < 4; ++j) {
                    int kl = kg * 4 + j; kl = (kl > 25) ? 25 : kl;
                    const float hv = hA[(hc + h) * STRIDE + 3 * kl + tap];
                    pacc[j][0] = fmaf(hv, w.x, pacc[j][0]);
                    pacc[j][1] = fmaf(hv, w.y, pacc[j][1]);
                    pacc[j][2] = fmaf(hv, w.z, pacc[j][2]);
                    pacc[j][3] = fmaf(hv, w.w, pacc[j][3]);
                }
            }
        }
    }

    const float fcb0 = fcb[0];
    const float4 pbv = *(const float4*)&pb[oo];
    const float4 fwv = *(const float4*)&fcw[oo];
    const int nch = nch_s;
    #pragma unroll
    for (int j = 0; j < 4; ++j) {
        float s = fmaxf(pacc[j][0] + pbv.x, 0.f) * fwv.x
                + fmaxf(pacc[j][1] + pbv.y, 0.f) * fwv.y
                + fmaxf(pacc[j][2] + pbv.z, 0.f) * fwv.z
                + fmaxf(pacc[j][3] + pbv.w, 0.f) * fwv.w;
        #pragma unroll
        for (int m = 1; m < 32; m <<= 1) s += __shfl_xor(s, m, 64);
        if (og == 0) {
            const int kl = kg * 4 + j;
            const int kG = jt * 26 + kl;
            if (kl < 26 && kG < KCH)
                out[b * KCH + kG] = (kG < nch) ? (s + fcb0) : 0.f;
        }
    }
}

extern "C" void kernel_launch(void* const* d_in, const int* in_sizes, int n_in,
                              void* d_out, int out_size, void* d_ws, size_t ws_size,
                              hipStream_t stream) {
    (void)in_sizes; (void)n_in; (void)out_size;
    const float* x    = (const float*)d_in[0];
    const int*   seq  = (const int*)d_in[1];
    const float* w0   = (const float*)d_in[2];
    const float* b0   = (const float*)d_in[3];
    const float* w1   = (const float*)d_in[4];
    const float* b1   = (const float*)d_in[5];
    const float* w2   = (const float*)d_in[6];
    const float* b2   = (const float*)d_in[7];
    const float* bng  = (const float*)d_in[8];
    const float* bnb  = (const float*)d_in[9];
    const float* bnm  = (const float*)d_in[10];
    const float* bnv  = (const float*)d_in[11];
    const float* pw   = (const float*)d_in[12];
    const float* pb   = (const float*)d_in[13];
    const float* fcw  = (const float*)d_in[14];
    const float* fcb  = (const float*)d_in[15];
    float* out = (float*)d_out;

    const size_t need = (size_t)3 * 12 * 8 * 2 * 1024;   // 589824 B of packed frags
    if (ws_size >= need) {
        unsigned short* wpk = (unsigned short*)d_ws;
        pack_w_frags<<<72, 256, 0, stream>>>(w1, w2, pw, wpk);
        fused_mfma<<<BB * NTB2, 256, 0, stream>>>(x, seq, w0, b0, b1, b2,
                                                  bng, bnb, bnm, bnv,
                                                  pb, fcw, fcb, wpk, out);
    } else {
        fused_pd<<<BB * NTB, 256, 0, stream>>>(x, seq, w0, b0, w1, b1, w2, b2,
                                               bng, bnb, bnm, bnv, pw, pb, fcw, fcb,
                                               out);
    }
}

// Round 8
// 100.476 us; speedup vs baseline: 5.4647x; 5.4647x over previous
//
#include <hip/hip_runtime.h>

#define BB   64
#define S    2048
#define HH   128
#define KCH  682
#define EPS  1e-5f

// ================= MFMA path (fp16 2-term: W=hi+lo(x1024), h single fp16) ===========
#define TT2   48          // output t per block (16 chunks)
#define NTB2  43          // ceil(2046/48)
#define NROWS 66          // h rows: t in [t0-3, t0+63)

typedef __attribute__((ext_vector_type(8))) _Float16 f16x8;
typedef __attribute__((ext_vector_type(8))) unsigned short u16x8;
typedef __attribute__((ext_vector_type(4))) unsigned short u16x4;
typedef __attribute__((ext_vector_type(4))) float f32x4;

__device__ __forceinline__ unsigned short f2h(float v) {
    union { _Float16 h; unsigned short u; } c;
    c.h = (_Float16)v;              // round-to-nearest
    return c.u;
}

// Pack W fragments in MFMA A-operand order (row=lane&15, k=(lane>>4)*8+j).
// plane 0: fp16(W); plane 1: fp16(1024*(W - fp16(W)))  [normal-range lo]
// frag_idx = ((mat*12+kb)*8+mc)*2+pl ; 512 ushort per frag (64 lanes x 8).
__global__ void pack_w_frags(const float* __restrict__ w1, const float* __restrict__ w2,
                             const float* __restrict__ pw, unsigned short* __restrict__ wpk) {
    int u = blockIdx.x * 256 + threadIdx.x;     // 18432 units
    if (u >= 18432) return;
    int lane = u & 63, mc = (u >> 6) & 7, kb = (u >> 9) % 12, mat = u / 6144;
    const float* src = (mat == 0) ? w1 : (mat == 1) ? w2 : pw;
    int c = mc * 16 + (lane & 15);
    int kbase = kb * 32 + ((lane >> 4) << 3);
    u16x8 hv, lv;
    #pragma unroll
    for (int j = 0; j < 8; ++j) {
        int k = kbase + j, tap = k >> 7, ci = k & 127;   // K = tap*128 + ci
        float v = src[c * 384 + ci * 3 + tap];
        union { _Float16 h; unsigned short us; } ch;
        ch.h = (_Float16)v;
        float r = (v - (float)ch.h) * 1024.0f;           // exact pow2 scale
        hv[j] = ch.us;
        lv[j] = f2h(r);
    }
    int fb = ((mat * 12 + kb) * 8 + mc) * 2;
    *(u16x8*)(wpk + (size_t)(fb + 0) * 512 + lane * 8) = hv;
    *(u16x8*)(wpk + (size_t)(fb + 1) * 512 + lane * 8) = lv;
}

__device__ __forceinline__ int read_seqlen(const int* seq, int b) {
    bool is64 = true;
    for (int i = 1; i < 64; i += 2) { if (seq[i] != 0) { is64 = false; break; } }
    return is64 ? seq[2 * b] : seq[b];
}

// swizzled byte address into the [NROWS][128] fp16 plane: row rr, 16B-chunk index
__device__ __forceinline__ int haddr(int rr, int chunk) {
    return (rr << 8) | ((chunk ^ (rr & 15)) << 4);
}

// Tc=2 c-tiles (by wv), NT n-tiles; B rows = RBASE + tap + (lane&15) + nt*16.
// Per (kb,nt): 1 B-read (fp16), scaled copy bs = bh*2^-10, 4 MFMAs.
template<int NT, int RBASE>
__device__ __forceinline__ void conv_f16(
        f32x4 (&acc)[2][NT], const unsigned short* __restrict__ wpk, int mat,
        const unsigned short* __restrict__ hH, int wv, int lane) {
    #pragma unroll
    for (int m = 0; m < 2; ++m)
        #pragma unroll
        for (int n = 0; n < NT; ++n) acc[m][n] = (f32x4){0.f, 0.f, 0.f, 0.f};

    const f16x8* wp = (const f16x8*)wpk;
    const _Float16 SC = (_Float16)0.0009765625f;     // 2^-10, exact
    for (int kb = 0; kb < 12; ++kb) {
        const int fb = ((mat * 12 + kb) * 8 + wv * 2) * 2;   // this wave's 2 c-tiles
        f16x8 a0h = wp[(size_t)(fb + 0) * 64 + lane];
        f16x8 a0l = wp[(size_t)(fb + 1) * 64 + lane];
        f16x8 a1h = wp[(size_t)(fb + 2) * 64 + lane];
        f16x8 a1l = wp[(size_t)(fb + 3) * 64 + lane];
        const int tap = kb >> 2;
        const int chunk = (kb & 3) * 4 + (lane >> 4);
        const int rr0 = RBASE + tap + (lane & 15);
        __builtin_amdgcn_s_setprio(1);
        #pragma unroll
        for (int nt = 0; nt < NT; ++nt) {
            const int ad = haddr(rr0 + nt * 16, chunk);
            f16x8 bh = *(const f16x8*)((const char*)hH + ad);
            f16x8 bs = bh * SC;                       // v_pk_mul_f16 x4
            acc[0][nt] = __builtin_amdgcn_mfma_f32_16x16x32_f16(a0h, bh, acc[0][nt], 0, 0, 0);
            acc[0][nt] = __builtin_amdgcn_mfma_f32_16x16x32_f16(a0l, bs, acc[0][nt], 0, 0, 0);
            acc[1][nt] = __builtin_amdgcn_mfma_f32_16x16x32_f16(a1h, bh, acc[1][nt], 0, 0, 0);
            acc[1][nt] = __builtin_amdgcn_mfma_f32_16x16x32_f16(a1l, bs, acc[1][nt], 0, 0, 0);
        }
        __builtin_amdgcn_s_setprio(0);
    }
}

// BN+relu epilogue: output tt=nt*16+(lane&15), t=t0+T_OFF+tt, row rr=tt+ROW_OFF (single plane)
template<int NT, int ROW_OFF, int T_OFF>
__device__ __forceinline__ void epi_f16(
        f32x4 (&acc)[2][NT], const float* __restrict__ bias,
        const float* __restrict__ bng, const float* __restrict__ bnb,
        const float* __restrict__ bnm, const float* __restrict__ bnv, int layer,
        unsigned short* __restrict__ hH, int wv, int lane, int t0) {
    #pragma unroll
    for (int m = 0; m < 2; ++m) {
        const int c0 = (wv * 2 + m) * 16 + (lane >> 4) * 4;
        const float4 bv = *(const float4*)&bias[c0];
        const float4 g  = *(const float4*)&bng[layer * 128 + c0];
        const float4 be = *(const float4*)&bnb[layer * 128 + c0];
        const float4 mn = *(const float4*)&bnm[layer * 128 + c0];
        const float4 vr = *(const float4*)&bnv[layer * 128 + c0];
        const float av[4] = { g.x * rsqrtf(vr.x + EPS), g.y * rsqrtf(vr.y + EPS),
                              g.z * rsqrtf(vr.z + EPS), g.w * rsqrtf(vr.w + EPS) };
        const float dv[4] = { be.x - mn.x * av[0], be.y - mn.y * av[1],
                              be.z - mn.z * av[2], be.w - mn.w * av[3] };
        const float bb[4] = { bv.x, bv.y, bv.z, bv.w };
        const int byte = c0 * 2, chunk = byte >> 4, off = byte & 15;
        #pragma unroll
        for (int nt = 0; nt < NT; ++nt) {
            const int tt = nt * 16 + (lane & 15);
            const int t = t0 + T_OFF + tt;
            const int rr = tt + ROW_OFF;
            const bool ok = (t >= 0) && (t < S);
            u16x4 h4;
            #pragma unroll
            for (int r = 0; r < 4; ++r) {
                float v = 0.f;
                if (ok) v = fmaf(fmaxf(acc[m][nt][r] + bb[r], 0.f), av[r], dv[r]);
                h4[r] = f2h(v);
            }
            *(u16x4*)((char*)hH + (haddr(rr, chunk) | off)) = h4;
        }
    }
}

__global__ __launch_bounds__(256, 4)
void fused_mfma(const float* __restrict__ x, const int* __restrict__ seq,
                const float* __restrict__ w0, const float* __restrict__ b0,
                const float* __restrict__ b1, const float* __restrict__ b2,
                const float* __restrict__ bng, const float* __restrict__ bnb,
                const float* __restrict__ bnm, const float* __restrict__ bnv,
                const float* __restrict__ pb, const float* __restrict__ fcw,
                const float* __restrict__ fcb, const unsigned short* __restrict__ wpk,
                float* __restrict__ out) {
    __shared__ __align__(16) unsigned short hH[NROWS * 128];    // 16896 B, single fp16 plane
    __shared__ __align__(16) float xs[72];
    __shared__ float p0[6 * 128];
    __shared__ float zred[4][16];
    __shared__ int nch_s;

    const int tid = threadIdx.x;
    const int lane = tid & 63, wv = tid >> 6;
    const int b  = blockIdx.x / NTB2;
    const int jt = blockIdx.x - b * NTB2;
    const int t0 = jt * TT2;

    // ---- stage x (t0-4 .. t0+63) + conv0/bn0 per-channel constants ----
    if (tid < 68) {
        const int t = t0 - 4 + tid;
        xs[tid] = (t >= 0 && t < S) ? x[b * S + t] : 0.f;
    }
    if (tid < 128) {
        const int c = tid;
        p0[c]         = w0[c * 3 + 0];
        p0[128 + c]   = w0[c * 3 + 1];
        p0[2*128 + c] = w0[c * 3 + 2];
        p0[3*128 + c] = b0[c];
        const float a0 = bng[c] * rsqrtf(bnv[c] + EPS);
        p0[4*128 + c] = a0;
        p0[5*128 + c] = bnb[c] - bnm[c] * a0;
    }
    if (tid == 0) nch_s = read_seqlen(seq, b) / 3;
    __syncthreads();

    // ---- conv0 + bn0 -> h1 rows rr=0..65 (t = t0-3+rr), single fp16 ----
    for (int it = 0; it < 5; ++it) {
        const int u = tid + it * 256;              // 1056 units = 66 rows x 16 octets
        if (u < NROWS * 16) {
            const int rr = u >> 4, oct = u & 15, ci0 = oct * 8;
            const int t = t0 - 3 + rr;
            const bool ok = (t >= 0) && (t < S);
            const float xm = xs[rr], xc = xs[rr + 1], xp = xs[rr + 2];
            u16x8 hv;
            #pragma unroll
            for (int q = 0; q < 8; ++q) {
                const int c = ci0 + q;
                float v = 0.f;
                if (ok) {
                    float sa = fmaf(xp, p0[2*128 + c],
                               fmaf(xc, p0[128 + c],
                               fmaf(xm, p0[c], p0[3*128 + c])));
                    v = fmaf(fmaxf(sa, 0.f), p0[4*128 + c], p0[5*128 + c]);
                }
                hv[q] = f2h(v);
            }
            *(u16x8*)((char*)hH + haddr(rr, oct)) = hv;
        }
    }
    __syncthreads();

    // ---- conv1: B rows 0..65 -> out rows tt+1 (1..64), t = t0-2+tt ----
    {
        f32x4 acc1[2][4];
        conv_f16<4, 0>(acc1, wpk, 0, hH, wv, lane);
        __syncthreads();                            // all h1 reads done
        epi_f16<4, 1, -2>(acc1, b1, bng, bnb, bnm, bnv, 1, hH, wv, lane, t0);
    }
    __syncthreads();

    // ---- conv2: B rows 2..64 -> out rows tt+3 (3..50), t = t0+tt ----
    {
        f32x4 acc2[2][3];
        conv_f16<3, 2>(acc2, wpk, 1, hH, wv, lane);
        __syncthreads();                            // all h2 reads done
        epi_f16<3, 3, 0>(acc2, b2, bng, bnb, bnm, bnv, 2, hH, wv, lane, t0);
    }
    __syncthreads();

    // ---- pre einsum: z[k][o], k = lane&15 (16 chunks), rows 3+3k+tap ----
    f32x4 pacc[2];
    pacc[0] = (f32x4){0.f, 0.f, 0.f, 0.f};
    pacc[1] = (f32x4){0.f, 0.f, 0.f, 0.f};
    {
        const f16x8* wp = (const f16x8*)wpk;
        const _Float16 SC = (_Float16)0.0009765625f;
        const int klocal = lane & 15;
        for (int kb = 0; kb < 12; ++kb) {
            const int fb = ((2 * 12 + kb) * 8 + wv * 2) * 2;
            f16x8 a0h = wp[(size_t)(fb + 0) * 64 + lane];
            f16x8 a0l = wp[(size_t)(fb + 1) * 64 + lane];
            f16x8 a1h = wp[(size_t)(fb + 2) * 64 + lane];
            f16x8 a1l = wp[(size_t)(fb + 3) * 64 + lane];
            const int tap = kb >> 2;
            const int chunk = (kb & 3) * 4 + (lane >> 4);
            const int rr = 3 + 3 * klocal + tap;          // h3 row for t = t0+3k+tap
            const int ad = haddr(rr, chunk);
            f16x8 bh = *(const f16x8*)((const char*)hH + ad);
            f16x8 bs = bh * SC;
            __builtin_amdgcn_s_setprio(1);
            pacc[0] = __builtin_amdgcn_mfma_f32_16x16x32_f16(a0h, bh, pacc[0], 0, 0, 0);
            pacc[0] = __builtin_amdgcn_mfma_f32_16x16x32_f16(a0l, bs, pacc[0], 0, 0, 0);
            pacc[1] = __builtin_amdgcn_mfma_f32_16x16x32_f16(a1h, bh, pacc[1], 0, 0, 0);
            pacc[1] = __builtin_amdgcn_mfma_f32_16x16x32_f16(a1l, bs, pacc[1], 0, 0, 0);
            __builtin_amdgcn_s_setprio(0);
        }
    }

    // ---- relu(z+pb)*fcw, reduce over o ----
    float s0 = 0.f;
    #pragma unroll
    for (int m = 0; m < 2; ++m) {
        const int o0 = (wv * 2 + m) * 16 + (lane >> 4) * 4;
        const float4 pbv = *(const float4*)&pb[o0];
        const float4 fwv = *(const float4*)&fcw[o0];
        const float pbb[4] = { pbv.x, pbv.y, pbv.z, pbv.w };
        const float fww[4] = { fwv.x, fwv.y, fwv.z, fwv.w };
        #pragma unroll
        for (int r = 0; r < 4; ++r)
            s0 += fmaxf(pacc[m][r] + pbb[r], 0.f) * fww[r];
    }
    s0 += __shfl_xor(s0, 16);
    s0 += __shfl_xor(s0, 32);                      // sum over o within wave's 32 channels
    if (lane < 16) zred[wv][lane] = s0;            // k = lane
    __syncthreads();
    if (tid < 16) {
        const float zz = zred[0][tid] + zred[1][tid] + zred[2][tid] + zred[3][tid];
        const int kG = jt * 16 + tid;
        if (kG < KCH)
            out[b * KCH + kG] = (kG < nch_s) ? (zz + fcb[0]) : 0.f;
    }
}

// ================= fp32 fallback (round-3 verified) =================
#define TT   78
#define NTB  27
#define STRIDE 84

__device__ __forceinline__ void stage_w_fb(float* __restrict__ wtS,
                                           const float* __restrict__ wraw, int cc, int tid) {
    for (int i = tid; i < 6144; i += 256)
        wtS[i] = wraw[(i & 127) * 384 + cc * 3 + (i >> 7)];
}

__device__ __forceinline__ void conv_gemm_fb(float (&acc)[10][4],
                                             const float* __restrict__ wraw,
                                             const float* __restrict__ hAp,
                                             float* __restrict__ wtS,
                                             int tid, int c0, int tbase) {
    #pragma unroll
    for (int i = 0; i < 10; ++i)
        #pragma unroll
        for (int q = 0; q < 4; ++q) acc[i][q] = 0.f;
    for (int cc = 0; cc < HH; cc += 16) {
        __syncthreads();
        stage_w_fb(wtS, wraw, cc, tid);
        __syncthreads();
        for (int ci = 0; ci < 16; ++ci) {
            float hr[12];
            #pragma unroll
            for (int j = 0; j < 12; ++j) hr[j] = hAp[(cc + ci) * STRIDE + tbase + j];
            #pragma unroll
            for (int tap = 0; tap < 3; ++tap) {
                const float4 w = *(const float4*)&wtS[((ci * 3 + tap) << 7) + c0];
                #pragma unroll
                for (int i = 0; i < 10; ++i) {
                    const float h = hr[i + tap];
                    acc[i][0] = fmaf(h, w.x, acc[i][0]);
                    acc[i][1] = fmaf(h, w.y, acc[i][1]);
                    acc[i][2] = fmaf(h, w.z, acc[i][2]);
                    acc[i][3] = fmaf(h, w.w, acc[i][3]);
                }
            }
        }
    }
}

__global__ __launch_bounds__(256, 2)
void fused_pd(const float* __restrict__ x, const int* __restrict__ seq,
              const float* __restrict__ w0, const float* __restrict__ b0,
              const float* __restrict__ w1raw, const float* __restrict__ b1,
              const float* __restrict__ w2raw, const float* __restrict__ b2,
              const float* __restrict__ bng, const float* __restrict__ bnb,
              const float* __restrict__ bnm, const float* __restrict__ bnv,
              const float* __restrict__ pwraw, const float* __restrict__ pb,
              const float* __restrict__ fcw, const float* __restrict__ fcb,
              float* __restrict__ out) {
    __shared__ __align__(16) float hA[HH * STRIDE];
    __shared__ __align__(16) float wtS[6144];
    __shared__ __align__(16) float xsf[TT + 8];
    __shared__ int nch_s;

    const int tid = threadIdx.x;
    const int b  = blockIdx.x / NTB;
    const int jt = blockIdx.x - b * NTB;
    const int t0 = jt * TT;

    for (int j = tid; j < TT + 6; j += 256) {
        const int t = t0 - 3 + j;
        xsf[j] = (t >= 0 && t < S) ? x[b * S + t] : 0.f;
    }
    if (tid == 0) nch_s = read_seqlen(seq, b) / 3;

    const int cch = tid & 127;
    const float w0a = w0[cch * 3 + 0], w0b = w0[cch * 3 + 1], w0c = w0[cch * 3 + 2];
    const float bb0 = b0[cch];
    const float a0 = bng[cch] * rsqrtf(bnv[cch] + EPS);
    const float d0 = bnb[cch] - bnm[cch] * a0;
    __syncthreads();

    for (int i = tid; i < (TT + 4) * HH; i += 256) {
        const int ttl = i >> 7;
        const int t = t0 - 2 + ttl;
        float v = 0.f;
        if (t >= 0 && t < S) {
            float sa = fmaf(xsf[ttl + 2], w0c, fmaf(xsf[ttl + 1], w0b, fmaf(xsf[ttl], w0a, bb0)));
            v = fmaf(fmaxf(sa, 0.f), a0, d0);
        }
        hA[cch * STRIDE + ttl] = v;
    }

    const int cg = tid & 31, tg = tid >> 5;
    const int c0 = cg * 4;
    const int tbase = tg * 10;
    float acc[10][4];

    conv_gemm_fb(acc, w1raw, hA, wtS, tid, c0, tbase);
    {
        const float4 bv = *(const float4*)&b1[c0];
        const float4 g  = *(const float4*)&bng[HH + c0];
        const float4 be = *(const float4*)&bnb[HH + c0];
        const float4 mn = *(const float4*)&bnm[HH + c0];
        const float4 vr = *(const float4*)&bnv[HH + c0];
        float av[4] = { g.x * rsqrtf(vr.x + EPS), g.y * rsqrtf(vr.y + EPS),
                        g.z * rsqrtf(vr.z + EPS), g.w * rsqrtf(vr.w + EPS) };
        float dv[4] = { be.x - mn.x * av[0], be.y - mn.y * av[1],
                        be.z - mn.z * av[2], be.w - mn.w * av[3] };
        float bb[4] = { bv.x, bv.y, bv.z, bv.w };
        __syncthreads();
        #pragma unroll
        for (int i = 0; i < 10; ++i) {
            const int tt2 = tbase + i;
            const int t = t0 - 1 + tt2;
            const bool ok = (t >= 0) && (t < S);
            #pragma unroll
            for (int q = 0; q < 4; ++q) {
                float v = 0.f;
                if (ok) v = fmaf(fmaxf(acc[i][q] + bb[q], 0.f), av[q], dv[q]);
                hA[(c0 + q) * STRIDE + tt2] = v;
            }
        }
        __syncthreads();
    }

    conv_gemm_fb(acc, w2raw, hA, wtS, tid, c0, tbase);
    {
        const float4 bv = *(const float4*)&b2[c0];
        const float4 g  = *(const float4*)&bng[2 * HH + c0];
        const float4 be = *(const float4*)&bnb[2 * HH + c0];
        const float4 mn = *(const float4*)&bnm[2 * HH + c0];
        const float4 vr = *(const float4*)&bnv[2 * HH + c0];
        float av[4] = { g.x * rsqrtf(vr.x + EPS), g.y * rsqrtf(vr.y + EPS),
                        g.z * rsqrtf(vr.z + EPS), g.w * rsqrtf(vr.w + EPS) };
        float dv[4] = { be.x - mn.x * av[0], be.y - mn.y * av[1],
                        be.z - mn.z * av[2], be.w - mn.w * av[3] };
        float bb[4] = { bv.x, bv.y, bv.z, bv.w };
        __syncthreads();
        #pragma unroll
        for (int i = 0; i < 10; ++i) {
            const int tt3 = tbase + i;
            if (tt3 < TT) {
                const int t = t0 + tt3;
                #pragma unroll
                for (int q = 0; q < 4; ++q) {
                    float vv = 0.f;
                    if (t < S) vv = fmaf(fmaxf(acc[i][q] + bb[q], 0.f), av[q], dv[q]);
                    hA[(c0 + q) * STRIDE + tt3] = vv;
                }
            }
        }
        __syncthreads();
    }

    const int og = tid & 31, kg = tid >> 5;
    const int oo = og * 4;
    float pacc[4][4];
    #pragma unroll
    for (int j = 0; j < 4; ++j)
        #pragma unroll
        for (int q = 0; q < 4; ++q) pacc[j][q] = 0.f;

    for (int hc = 0; hc < HH; hc += 16) {
        __syncthreads();
        stage_w_fb(wtS, pwraw, hc, tid);
        __syncthreads();
        for (int h = 0; h < 16; ++h) {
            #pragma unroll
            for (int tap = 0; tap < 3; ++tap) {
                const float4 w = *(const float4*)&wtS[((h * 3 + tap) << 7) + oo];
                #pragma unroll
                for (int j = 0; j < 4; ++j) {
                    int kl = kg * 4 + j; kl = (kl > 25) ? 25 : kl;
                    const float hv = hA[(hc + h) * STRIDE + 3 * kl + tap];
                    pacc[j][0] = fmaf(hv, w.x, pacc[j][0]);
                    pacc[j][1] = fmaf(hv, w.y, pacc[j][1]);
                    pacc[j][2] = fmaf(hv, w.z, pacc[j][2]);
                    pacc[j][3] = fmaf(hv, w.w, pacc[j][3]);
                }
            }
        }
    }

    const float fcb0 = fcb[0];
    const float4 pbv = *(const float4*)&pb[oo];
    const float4 fwv = *(const float4*)&fcw[oo];
    const int nch = nch_s;
    #pragma unroll
    for (int j = 0; j < 4; ++j) {
        float s = fmaxf(pacc[j][0] + pbv.x, 0.f) * fwv.x
                + fmaxf(pacc[j][1] + pbv.y, 0.f) * fwv.y
                + fmaxf(pacc[j][2] + pbv.z, 0.f) * fwv.z
                + fmaxf(pacc[j][3] + pbv.w, 0.f) * fwv.w;
        #pragma unroll
        for (int m = 1; m < 32; m <<= 1) s += __shfl_xor(s, m, 64);
        if (og == 0) {
            const int kl = kg * 4 + j;
            const int kG = jt * 26 + kl;
            if (kl < 26 && kG < KCH)
                out[b * KCH + kG] = (kG < nch) ? (s + fcb0) : 0.f;
        }
    }
}

extern "C" void kernel_launch(void* const* d_in, const int* in_sizes, int n_in,
                              void* d_out, int out_size, void* d_ws, size_t ws_size,
                              hipStream_t stream) {
    (void)in_sizes; (void)n_in; (void)out_size;
    const float* x    = (const float*)d_in[0];
    const int*   seq  = (const int*)d_in[1];
    const float* w0   = (const float*)d_in[2];
    const float* b0   = (const float*)d_in[3];
    const float* w1   = (const float*)d_in[4];
    const float* b1   = (const float*)d_in[5];
    const float* w2   = (const float*)d_in[6];
    const float* b2   = (const float*)d_in[7];
    const float* bng  = (const float*)d_in[8];
    const float* bnb  = (const float*)d_in[9];
    const float* bnm  = (const float*)d_in[10];
    const float* bnv  = (const float*)d_in[11];
    const float* pw   = (const float*)d_in[12];
    const float* pb   = (const float*)d_in[13];
    const float* fcw  = (const float*)d_in[14];
    const float* fcb  = (const float*)d_in[15];
    float* out = (float*)d_out;

    const size_t need = (size_t)3 * 12 * 8 * 2 * 1024;   // 589824 B of packed frags
    if (ws_size >= need) {
        unsigned short* wpk = (unsigned short*)d_ws;
        pack_w_frags<<<72, 256, 0, stream>>>(w1, w2, pw, wpk);
        fused_mfma<<<BB * NTB2, 256, 0, stream>>>(x, seq, w0, b0, b1, b2,
                                                  bng, bnb, bnm, bnv,
                                                  pb, fcw, fcb, wpk, out);
    } else {
        fused_pd<<<BB * NTB, 256, 0, stream>>>(x, seq, w0, b0, w1, b1, w2, b2,
                                               bng, bnb, bnm, bnv, pw, pb, fcw, fcb,
                                               out);
    }
}

// Round 9
// 77.580 us; speedup vs baseline: 7.0775x; 1.2951x over previous
//
#include <hip/hip_runtime.h>

#define BB   64
#define S    2048
#define HH   128
#define KCH  682
#define EPS  1e-5f

// ===== MFMA path: one-term fp16 W + fp16 h, 512-thr blocks (4cg x 2ng waves), TT=96 =====
#define TT2   96
#define NTB2  22          // ceil(2046/96)
#define NROWS 114         // rows rr: t = t0-3+rr

typedef __attribute__((ext_vector_type(8))) _Float16 f16x8;
typedef __attribute__((ext_vector_type(8))) unsigned short u16x8;
typedef __attribute__((ext_vector_type(4))) unsigned short u16x4;
typedef __attribute__((ext_vector_type(4))) float f32x4;

__device__ __forceinline__ unsigned short f2h(float v) {
    union { _Float16 h; unsigned short u; } c;
    c.h = (_Float16)v;              // round-to-nearest
    return c.u;
}

// Pack W fragments, single fp16 plane, MFMA A-order (row=lane&15, k=(lane>>4)*8+j).
// frag_idx = (mat*12+kb)*8+mc ; 512 ushort per frag. wpk = 288 KB.
__global__ void pack_w_frags(const float* __restrict__ w1, const float* __restrict__ w2,
                             const float* __restrict__ pw, unsigned short* __restrict__ wpk) {
    int u = blockIdx.x * 256 + threadIdx.x;     // 18432 units = 288 frags x 64 lanes
    if (u >= 18432) return;
    int lane = u & 63, mc = (u >> 6) & 7, kb = (u >> 9) % 12, mat = u / 6144;
    const float* src = (mat == 0) ? w1 : (mat == 1) ? w2 : pw;
    int c = mc * 16 + (lane & 15);
    int kbase = kb * 32 + ((lane >> 4) << 3);
    u16x8 hv;
    #pragma unroll
    for (int j = 0; j < 8; ++j) {
        int k = kbase + j, tap = k >> 7, ci = k & 127;   // K = tap*128 + ci
        hv[j] = f2h(src[c * 384 + ci * 3 + tap]);
    }
    *(u16x8*)(wpk + (size_t)((mat * 12 + kb) * 8 + mc) * 512 + lane * 8) = hv;
}

__device__ __forceinline__ int read_seqlen(const int* seq, int b) {
    bool is64 = true;
    for (int i = 1; i < 64; i += 2) { if (seq[i] != 0) { is64 = false; break; } }
    return is64 ? seq[2 * b] : seq[b];
}

// swizzled byte address into the [NROWS][128] fp16 plane: row rr, 16B-chunk index
__device__ __forceinline__ int haddr(int rr, int chunk) {
    return (rr << 8) | ((chunk ^ (rr & 15)) << 4);
}

// C=2 mc-tiles (by cg), up to NT n-tiles; B rows = rbase + tap + (lane&15) + nt*16.
// One A-term: 1 B-read -> 2 MFMAs.
template<int NT>
__device__ __forceinline__ void conv_f16(
        f32x4 (&acc)[2][NT], const unsigned short* __restrict__ wpk, int mat,
        const unsigned short* __restrict__ hH, int cg, int nt_base, int nt_lim,
        int rbase, int lane) {
    #pragma unroll
    for (int m = 0; m < 2; ++m)
        #pragma unroll
        for (int j = 0; j < NT; ++j) acc[m][j] = (f32x4){0.f, 0.f, 0.f, 0.f};

    const f16x8* wp = (const f16x8*)wpk;
    for (int kb = 0; kb < 12; ++kb) {
        const int fb = (mat * 12 + kb) * 8 + cg * 2;
        f16x8 a0 = wp[(size_t)(fb + 0) * 64 + lane];
        f16x8 a1 = wp[(size_t)(fb + 1) * 64 + lane];
        const int tap = kb >> 2;
        const int chunk = (kb & 3) * 4 + (lane >> 4);
        const int rr0 = rbase + tap + (lane & 15);
        __builtin_amdgcn_s_setprio(1);
        #pragma unroll
        for (int j = 0; j < NT; ++j) {
            const int nt = nt_base + j;            // wave-uniform guard
            if (nt < nt_lim) {
                const int ad = haddr(rr0 + nt * 16, chunk);
                f16x8 bh = *(const f16x8*)((const char*)hH + ad);
                acc[0][j] = __builtin_amdgcn_mfma_f32_16x16x32_f16(a0, bh, acc[0][j], 0, 0, 0);
                acc[1][j] = __builtin_amdgcn_mfma_f32_16x16x32_f16(a1, bh, acc[1][j], 0, 0, 0);
            }
        }
        __builtin_amdgcn_s_setprio(0);
    }
}

// BN+relu epilogue: output tt=(nt_base+j)*16+(lane&15), t=t0+T_OFF+tt, row rr=tt+ROW_OFF
template<int NT, int ROW_OFF, int T_OFF>
__device__ __forceinline__ void epi_f16(
        f32x4 (&acc)[2][NT], const float* __restrict__ bias,
        const float* __restrict__ bng, const float* __restrict__ bnb,
        const float* __restrict__ bnm, const float* __restrict__ bnv, int layer,
        unsigned short* __restrict__ hH, int cg, int nt_base, int nt_lim,
        int lane, int t0) {
    #pragma unroll
    for (int m = 0; m < 2; ++m) {
        const int c0 = (cg * 2 + m) * 16 + (lane >> 4) * 4;
        const float4 bv = *(const float4*)&bias[c0];
        const float4 g  = *(const float4*)&bng[layer * 128 + c0];
        const float4 be = *(const float4*)&bnb[layer * 128 + c0];
        const float4 mn = *(const float4*)&bnm[layer * 128 + c0];
        const float4 vr = *(const float4*)&bnv[layer * 128 + c0];
        const float av[4] = { g.x * rsqrtf(vr.x + EPS), g.y * rsqrtf(vr.y + EPS),
                              g.z * rsqrtf(vr.z + EPS), g.w * rsqrtf(vr.w + EPS) };
        const float dv[4] = { be.x - mn.x * av[0], be.y - mn.y * av[1],
                              be.z - mn.z * av[2], be.w - mn.w * av[3] };
        const float bb[4] = { bv.x, bv.y, bv.z, bv.w };
        const int byte = c0 * 2, chunk = byte >> 4, off = byte & 15;
        #pragma unroll
        for (int j = 0; j < NT; ++j) {
            const int nt = nt_base + j;
            if (nt < nt_lim) {
                const int tt = nt * 16 + (lane & 15);
                const int t = t0 + T_OFF + tt;
                const int rr = tt + ROW_OFF;
                const bool ok = (t >= 0) && (t < S);
                u16x4 h4;
                #pragma unroll
                for (int r = 0; r < 4; ++r) {
                    float v = 0.f;
                    if (ok) v = fmaf(fmaxf(acc[m][j][r] + bb[r], 0.f), av[r], dv[r]);
                    h4[r] = f2h(v);
                }
                *(u16x4*)((char*)hH + (haddr(rr, chunk) | off)) = h4;
            }
        }
    }
}

__global__ __launch_bounds__(512, 8)
void fused_mfma(const float* __restrict__ x, const int* __restrict__ seq,
                const float* __restrict__ w0, const float* __restrict__ b0,
                const float* __restrict__ b1, const float* __restrict__ b2,
                const float* __restrict__ bng, const float* __restrict__ bnb,
                const float* __restrict__ bnm, const float* __restrict__ bnv,
                const float* __restrict__ pb, const float* __restrict__ fcw,
                const float* __restrict__ fcb, const unsigned short* __restrict__ wpk,
                float* __restrict__ out) {
    __shared__ __align__(16) unsigned short hH[NROWS * 128];    // 29184 B
    __shared__ __align__(16) float xs[116];
    __shared__ float p0[6 * 128];
    __shared__ float zred[4][2][16];
    __shared__ int nch_s;

    const int tid = threadIdx.x;
    const int lane = tid & 63, wv = tid >> 6;
    const int cg = wv & 3, ng = wv >> 2;      // 4 c-groups x 2 n-groups
    const int b  = blockIdx.x / NTB2;
    const int jt = blockIdx.x - b * NTB2;
    const int t0 = jt * TT2;

    // ---- stage x (t0-4 .. t0+111) + conv0/bn0 per-channel constants ----
    if (tid < 116) {
        const int t = t0 - 4 + tid;
        xs[tid] = (t >= 0 && t < S) ? x[b * S + t] : 0.f;
    }
    if (tid < 128) {
        const int c = tid;
        p0[c]         = w0[c * 3 + 0];
        p0[128 + c]   = w0[c * 3 + 1];
        p0[2*128 + c] = w0[c * 3 + 2];
        p0[3*128 + c] = b0[c];
        const float a0 = bng[c] * rsqrtf(bnv[c] + EPS);
        p0[4*128 + c] = a0;
        p0[5*128 + c] = bnb[c] - bnm[c] * a0;
    }
    if (tid == 0) nch_s = read_seqlen(seq, b) / 3;
    __syncthreads();

    // ---- conv0 + bn0 -> h1 rows rr=0..113 (t = t0-3+rr), single fp16 ----
    for (int it = 0; it < 4; ++it) {
        const int u = tid + it * 512;              // 1824 units = 114 rows x 16 octets
        if (u < NROWS * 16) {
            const int rr = u >> 4, oct = u & 15, ci0 = oct * 8;
            const int t = t0 - 3 + rr;
            const bool ok = (t >= 0) && (t < S);
            const float xm = xs[rr], xc = xs[rr + 1], xp = xs[rr + 2];
            u16x8 hv;
            #pragma unroll
            for (int q = 0; q < 8; ++q) {
                const int c = ci0 + q;
                float v = 0.f;
                if (ok) {
                    float sa = fmaf(xp, p0[2*128 + c],
                               fmaf(xc, p0[128 + c],
                               fmaf(xm, p0[c], p0[3*128 + c])));
                    v = fmaf(fmaxf(sa, 0.f), p0[4*128 + c], p0[5*128 + c]);
                }
                hv[q] = f2h(v);
            }
            *(u16x8*)((char*)hH + haddr(rr, oct)) = hv;
        }
    }
    __syncthreads();

    // ---- conv1: 7 n-tiles (tt 0..111 -> rows 1..112); ng0 {0..3}, ng1 {4..6} ----
    {
        f32x4 acc1[2][4];
        conv_f16<4>(acc1, wpk, 0, hH, cg, ng * 4, 7, 0, lane);
        __syncthreads();                            // all h1 reads done
        epi_f16<4, 1, -2>(acc1, b1, bng, bnb, bnm, bnv, 1, hH, cg, ng * 4, 7, lane, t0);
    }
    __syncthreads();

    // ---- conv2: 6 n-tiles (tt 0..95 -> rows 3..98); B rows 2..99; ng0 {0..2}, ng1 {3..5} ----
    {
        f32x4 acc2[2][3];
        conv_f16<3>(acc2, wpk, 1, hH, cg, ng * 3, 6, 2, lane);
        __syncthreads();                            // all h2 reads done
        epi_f16<3, 3, 0>(acc2, b2, bng, bnb, bnm, bnv, 2, hH, cg, ng * 3, 6, lane, t0);
    }
    __syncthreads();

    // ---- pre einsum: 32 chunks; ng owns k-tile (k = 16ng + (lane&15)); rows 3+3k+tap ----
    f32x4 pacc[2];
    pacc[0] = (f32x4){0.f, 0.f, 0.f, 0.f};
    pacc[1] = (f32x4){0.f, 0.f, 0.f, 0.f};
    {
        const f16x8* wp = (const f16x8*)wpk;
        const int klocal = ng * 16 + (lane & 15);
        for (int kb = 0; kb < 12; ++kb) {
            const int fb = (2 * 12 + kb) * 8 + cg * 2;
            f16x8 a0 = wp[(size_t)(fb + 0) * 64 + lane];
            f16x8 a1 = wp[(size_t)(fb + 1) * 64 + lane];
            const int tap = kb >> 2;
            const int chunk = (kb & 3) * 4 + (lane >> 4);
            const int rr = 3 + 3 * klocal + tap;          // h3 row for t = t0+3k+tap
            const int ad = haddr(rr, chunk);
            f16x8 bh = *(const f16x8*)((const char*)hH + ad);
            __builtin_amdgcn_s_setprio(1);
            pacc[0] = __builtin_amdgcn_mfma_f32_16x16x32_f16(a0, bh, pacc[0], 0, 0, 0);
            pacc[1] = __builtin_amdgcn_mfma_f32_16x16x32_f16(a1, bh, pacc[1], 0, 0, 0);
            __builtin_amdgcn_s_setprio(0);
        }
    }

    // ---- relu(z+pb)*fcw, reduce over this wave's 32 o-channels ----
    float s0 = 0.f;
    #pragma unroll
    for (int m = 0; m < 2; ++m) {
        const int o0 = (cg * 2 + m) * 16 + (lane >> 4) * 4;
        const float4 pbv = *(const float4*)&pb[o0];
        const float4 fwv = *(const float4*)&fcw[o0];
        const float pbb[4] = { pbv.x, pbv.y, pbv.z, pbv.w };
        const float fww[4] = { fwv.x, fwv.y, fwv.z, fwv.w };
        #pragma unroll
        for (int r = 0; r < 4; ++r)
            s0 += fmaxf(pacc[m][r] + pbb[r], 0.f) * fww[r];
    }
    s0 += __shfl_xor(s0, 16);
    s0 += __shfl_xor(s0, 32);
    if (lane < 16) zred[cg][ng][lane] = s0;        // k = 16ng + lane
    __syncthreads();
    if (tid < 32) {
        const int kt = tid >> 4, kl = tid & 15;
        const float zz = zred[0][kt][kl] + zred[1][kt][kl]
                       + zred[2][kt][kl] + zred[3][kt][kl];
        const int kG = jt * 32 + tid;
        if (kG < KCH)
            out[b * KCH + kG] = (kG < nch_s) ? (zz + fcb[0]) : 0.f;
    }
}

// ================= fp32 fallback (round-3 verified) =================
#define TT   78
#define NTB  27
#define STRIDE 84

__device__ __forceinline__ void stage_w_fb(float* __restrict__ wtS,
                                           const float* __restrict__ wraw, int cc, int tid) {
    for (int i = tid; i < 6144; i += 256)
        wtS[i] = wraw[(i & 127) * 384 + cc * 3 + (i >> 7)];
}

__device__ __forceinline__ void conv_gemm_fb(float (&acc)[10][4],
                                             const float* __restrict__ wraw,
                                             const float* __restrict__ hAp,
                                             float* __restrict__ wtS,
                                             int tid, int c0, int tbase) {
    #pragma unroll
    for (int i = 0; i < 10; ++i)
        #pragma unroll
        for (int q = 0; q < 4; ++q) acc[i][q] = 0.f;
    for (int cc = 0; cc < HH; cc += 16) {
        __syncthreads();
        stage_w_fb(wtS, wraw, cc, tid);
        __syncthreads();
        for (int ci = 0; ci < 16; ++ci) {
            float hr[12];
            #pragma unroll
            for (int j = 0; j < 12; ++j) hr[j] = hAp[(cc + ci) * STRIDE + tbase + j];
            #pragma unroll
            for (int tap = 0; tap < 3; ++tap) {
                const float4 w = *(const float4*)&wtS[((ci * 3 + tap) << 7) + c0];
                #pragma unroll
                for (int i = 0; i < 10; ++i) {
                    const float h = hr[i + tap];
                    acc[i][0] = fmaf(h, w.x, acc[i][0]);
                    acc[i][1] = fmaf(h, w.y, acc[i][1]);
                    acc[i][2] = fmaf(h, w.z, acc[i][2]);
                    acc[i][3] = fmaf(h, w.w, acc[i][3]);
                }
            }
        }
    }
}

__global__ __launch_bounds__(256, 2)
void fused_pd(const float* __restrict__ x, const int* __restrict__ seq,
              const float* __restrict__ w0, const float* __restrict__ b0,
              const float* __restrict__ w1raw, const float* __restrict__ b1,
              const float* __restrict__ w2raw, const float* __restrict__ b2,
              const float* __restrict__ bng, const float* __restrict__ bnb,
              const float* __restrict__ bnm, const float* __restrict__ bnv,
              const float* __restrict__ pwraw, const float* __restrict__ pb,
              const float* __restrict__ fcw, const float* __restrict__ fcb,
              float* __restrict__ out) {
    __shared__ __align__(16) float hA[HH * STRIDE];
    __shared__ __align__(16) float wtS[6144];
    __shared__ __align__(16) float xsf[TT + 8];
    __shared__ int nch_s;

    const int tid = threadIdx.x;
    const int b  = blockIdx.x / NTB;
    const int jt = blockIdx.x - b * NTB;
    const int t0 = jt * TT;

    for (int j = tid; j < TT + 6; j += 256) {
        const int t = t0 - 3 + j;
        xsf[j] = (t >= 0 && t < S) ? x[b * S + t] : 0.f;
    }
    if (tid == 0) nch_s = read_seqlen(seq, b) / 3;

    const int cch = tid & 127;
    const float w0a = w0[cch * 3 + 0], w0b = w0[cch * 3 + 1], w0c = w0[cch * 3 + 2];
    const float bb0 = b0[cch];
    const float a0 = bng[cch] * rsqrtf(bnv[cch] + EPS);
    const float d0 = bnb[cch] - bnm[cch] * a0;
    __syncthreads();

    for (int i = tid; i < (TT + 4) * HH; i += 256) {
        const int ttl = i >> 7;
        const int t = t0 - 2 + ttl;
        float v = 0.f;
        if (t >= 0 && t < S) {
            float sa = fmaf(xsf[ttl + 2], w0c, fmaf(xsf[ttl + 1], w0b, fmaf(xsf[ttl], w0a, bb0)));
            v = fmaf(fmaxf(sa, 0.f), a0, d0);
        }
        hA[cch * STRIDE + ttl] = v;
    }

    const int cg = tid & 31, tg = tid >> 5;
    const int c0 = cg * 4;
    const int tbase = tg * 10;
    float acc[10][4];

    conv_gemm_fb(acc, w1raw, hA, wtS, tid, c0, tbase);
    {
        const float4 bv = *(const float4*)&b1[c0];
        const float4 g  = *(const float4*)&bng[HH + c0];
        const float4 be = *(const float4*)&bnb[HH + c0];
        const float4 mn = *(const float4*)&bnm[HH + c0];
        const float4 vr = *(const float4*)&bnv[HH + c0];
        float av[4] = { g.x * rsqrtf(vr.x + EPS), g.y * rsqrtf(vr.y + EPS),
                        g.z * rsqrtf(vr.z + EPS), g.w * rsqrtf(vr.w + EPS) };
        float dv[4] = { be.x - mn.x * av[0], be.y - mn.y * av[1],
                        be.z - mn.z * av[2], be.w - mn.w * av[3] };
        float bb[4] = { bv.x, bv.y, bv.z, bv.w };
        __syncthreads();
        #pragma unroll
        for (int i = 0; i < 10; ++i) {
            const int tt2 = tbase + i;
            const int t = t0 - 1 + tt2;
            const bool ok = (t >= 0) && (t < S);
            #pragma unroll
            for (int q = 0; q < 4; ++q) {
                float v = 0.f;
                if (ok) v = fmaf(fmaxf(acc[i][q] + bb[q], 0.f), av[q], dv[q]);
                hA[(c0 + q) * STRIDE + tt2] = v;
            }
        }
        __syncthreads();
    }

    conv_gemm_fb(acc, w2raw, hA, wtS, tid, c0, tbase);
    {
        const float4 bv = *(const float4*)&b2[c0];
        const float4 g  = *(const float4*)&bng[2 * HH + c0];
        const float4 be = *(const float4*)&bnb[2 * HH + c0];
        const float4 mn = *(const float4*)&bnm[2 * HH + c0];
        const float4 vr = *(const float4*)&bnv[2 * HH + c0];
        float av[4] = { g.x * rsqrtf(vr.x + EPS), g.y * rsqrtf(vr.y + EPS),
                        g.z * rsqrtf(vr.z + EPS), g.w * rsqrtf(vr.w + EPS) };
        float dv[4] = { be.x - mn.x * av[0], be.y - mn.y * av[1],
                        be.z - mn.z * av[2], be.w - mn.w * av[3] };
        float bb[4] = { bv.x, bv.y, bv.z, bv.w };
        __syncthreads();
        #pragma unroll
        for (int i = 0; i < 10; ++i) {
            const int tt3 = tbase + i;
            if (tt3 < TT) {
                const int t = t0 + tt3;
                #pragma unroll
                for (int q = 0; q < 4; ++q) {
                    float vv = 0.f;
                    if (t < S) vv = fmaf(fmaxf(acc[i][q] + bb[q], 0.f), av[q], dv[q]);
                    hA[(c0 + q) * STRIDE + tt3] = vv;
                }
            }
        }
        __syncthreads();
    }

    const int og = tid & 31, kg = tid >> 5;
    const int oo = og * 4;
    float pacc[4][4];
    #pragma unroll
    for (int j = 0; j < 4; ++j)
        #pragma unroll
        for (int q = 0; q < 4; ++q) pacc[j][q] = 0.f;

    for (int hc = 0; hc < HH; hc += 16) {
        __syncthreads();
        stage_w_fb(wtS, pwraw, hc, tid);
        __syncthreads();
        for (int h = 0; h < 16; ++h) {
            #pragma unroll
            for (int tap = 0; tap < 3; ++tap) {
                const float4 w = *(const float4*)&wtS[((h * 3 + tap) << 7) + oo];
                #pragma unroll
                for (int j = 0; j < 4; ++j) {
                    int kl = kg * 4 + j; kl = (kl > 25) ? 25 : kl;
                    const float hv = hA[(hc + h) * STRIDE + 3 * kl + tap];
                    pacc[j][0] = fmaf(hv, w.x, pacc[j][0]);
                    pacc[j][1] = fmaf(hv, w.y, pacc[j][1]);
                    pacc[j][2] = fmaf(hv, w.z, pacc[j][2]);
                    pacc[j][3] = fmaf(hv, w.w, pacc[j][3]);
                }
            }
        }
    }

    const float fcb0 = fcb[0];
    const float4 pbv = *(const float4*)&pb[oo];
    const float4 fwv = *(const float4*)&fcw[oo];
    const int nch = nch_s;
    #pragma unroll
    for (int j = 0; j < 4; ++j) {
        float s = fmaxf(pacc[j][0] + pbv.x, 0.f) * fwv.x
                + fmaxf(pacc[j][1] + pbv.y, 0.f) * fwv.y
                + fmaxf(pacc[j][2] + pbv.z, 0.f) * fwv.z
                + fmaxf(pacc[j][3] + pbv.w, 0.f) * fwv.w;
        #pragma unroll
        for (int m = 1; m < 32; m <<= 1) s += __shfl_xor(s, m, 64);
        if (og == 0) {
            const int kl = kg * 4 + j;
            const int kG = jt * 26 + kl;
            if (kl < 26 && kG < KCH)
                out[b * KCH + kG] = (kG < nch) ? (s + fcb0) : 0.f;
        }
    }
}

extern "C" void kernel_launch(void* const* d_in, const int* in_sizes, int n_in,
                              void* d_out, int out_size, void* d_ws, size_t ws_size,
                              hipStream_t stream) {
    (void)in_sizes; (void)n_in; (void)out_size;
    const float* x    = (const float*)d_in[0];
    const int*   seq  = (const int*)d_in[1];
    const float* w0   = (const float*)d_in[2];
    const float* b0   = (const float*)d_in[3];
    const float* w1   = (const float*)d_in[4];
    const float* b1   = (const float*)d_in[5];
    const float* w2   = (const float*)d_in[6];
    const float* b2   = (const float*)d_in[7];
    const float* bng  = (const float*)d_in[8];
    const float* bnb  = (const float*)d_in[9];
    const float* bnm  = (const float*)d_in[10];
    const float* bnv  = (const float*)d_in[11];
    const float* pw   = (const float*)d_in[12];
    const float* pb   = (const float*)d_in[13];
    const float* fcw  = (const float*)d_in[14];
    const float* fcb  = (const float*)d_in[15];
    float* out = (float*)d_out;

    const size_t need = (size_t)3 * 12 * 8 * 1024;   // 294912 B of packed frags
    if (ws_size >= need) {
        unsigned short* wpk = (unsigned short*)d_ws;
        pack_w_frags<<<72, 256, 0, stream>>>(w1, w2, pw, wpk);
        fused_mfma<<<BB * NTB2, 512, 0, stream>>>(x, seq, w0, b0, b1, b2,
                                                  bng, bnb, bnm, bnv,
                                                  pb, fcw, fcb, wpk, out);
    } else {
        fused_pd<<<BB * NTB, 256, 0, stream>>>(x, seq, w0, b0, w1, b1, w2, b2,
                                               bng, bnb, bnm, bnv, pw, pb, fcw, fcb,
                                               out);
    }
}